// Round 2
// baseline (2210.191 us; speedup 1.0000x reference)
//
#include <hip/hip_runtime.h>
#include <stdint.h>

#define Bsz 64
#define Tsz 512
#define HD  512
#define GROUPS 4
#define MEMBERS 16
#define BROWS 16          // batch rows per group
#define JCH 32            // hidden units per workgroup
#define NWG (GROUPS*MEMBERS)
#define NTHR 512
#define LROW 520          // LDS row stride in halfwords (512 + 8 pad)
#define LROWD 260         // same in dwords
#define HSLOT (Bsz*HD/2)  // 16384 u64 per parity buffer

typedef __attribute__((ext_vector_type(8))) short bf16x8;
typedef __attribute__((ext_vector_type(4))) float f32x4;
typedef __attribute__((ext_vector_type(4))) uint32_t u32x4;
typedef __attribute__((ext_vector_type(2))) uint32_t u32x2;

// lgkm-only barrier: LDS producer/consumer hazards need lgkmcnt(0)+s_barrier ONLY.
// Deliberately does NOT drain vmcnt — global store acks / prefetch loads stay in
// flight across the barrier (the whole point of this revision).
#define BAR() asm volatile("s_waitcnt lgkmcnt(0)\n\ts_barrier" ::: "memory")

__device__ __forceinline__ uint32_t f2bf(float f) {
  uint32_t u = __builtin_bit_cast(uint32_t, f);
  return (u + 0x7FFFu + ((u >> 16) & 1u)) >> 16;   // RNE f32 -> bf16
}

// Load 8 consecutive f32 from W[row][k0..k0+7], convert to a bf16x8 MFMA B-fragment.
__device__ __forceinline__ bf16x8 ldwf(const float* __restrict__ W, int row, int k0) {
  const f32x4 a = *reinterpret_cast<const f32x4*>(W + (size_t)row * HD + k0);
  const f32x4 b = *reinterpret_cast<const f32x4*>(W + (size_t)row * HD + k0 + 4);
  bf16x8 r;
  r[0] = (short)f2bf(a.x); r[1] = (short)f2bf(a.y);
  r[2] = (short)f2bf(a.z); r[3] = (short)f2bf(a.w);
  r[4] = (short)f2bf(b.x); r[5] = (short)f2bf(b.y);
  r[6] = (short)f2bf(b.z); r[7] = (short)f2bf(b.w);
  return r;
}

// Prologue-only: stage x[b0..b0+15][0][:] (f32) into LDS as bf16 in one shot.
__device__ __forceinline__ void stage_x0(const float* __restrict__ x, int b0,
                                         uint32_t* xl, int tid) {
#pragma unroll
  for (int i = 0; i < 4; ++i) {
    const int fl = tid + i * 512;        // float4 index over 16x128
    const int row = fl >> 7;
    const int c4 = fl & 127;
    const f32x4 v = *reinterpret_cast<const f32x4*>(
        x + ((size_t)(b0 + row) * Tsz + 0) * HD + c4 * 4);
    u32x2 w;
    w.x = f2bf(v.x) | (f2bf(v.y) << 16);
    w.y = f2bf(v.z) | (f2bf(v.w) << 16);
    *reinterpret_cast<u32x2*>(xl + row * LROWD + c4 * 2) = w;
  }
}

// Exchange buffer hbx: u64[2][Bsz][256]. Each u64 = (tag << 32) | (2 packed bf16).
// h(s) lives at parity s&1 with tag s+1; h(-1)=h0 at parity 1 with tag 0.
__global__ void gru_init(const float* __restrict__ h0, uint64_t* __restrict__ hbx) {
  const int i = blockIdx.x * 256 + threadIdx.x;
  if (i < HSLOT) {
    const float a = h0[2 * i], b = h0[2 * i + 1];
    hbx[HSLOT + i] = (uint64_t)(f2bf(a) | (f2bf(b) << 16));  // parity 1: tag 0 | h0
    hbx[i] = 0xFFFFFFFF00000000ull;                          // parity 0: never-matching tag
  }
}

__global__ void __launch_bounds__(NTHR) gru_persist(
    const float* __restrict__ x, const float* __restrict__ h0,
    const float* __restrict__ Wih, const float* __restrict__ Whh,
    const float* __restrict__ bih, const float* __restrict__ bhh,
    const int* __restrict__ lens,
    float* __restrict__ out, float* __restrict__ outh,
    uint64_t* __restrict__ hbx) {
  __shared__ alignas(16) unsigned short x_lds[2][BROWS * LROW];
  __shared__ alignas(16) unsigned short h_lds[BROWS * LROW];
  __shared__ alignas(16) float s_lds[BROWS][4][JCH];   // [row][r,z,i_n,h_n][j]

  const int tid = threadIdx.x;
  const int lane = tid & 63;
  const int wv = tid >> 6;                 // wave 0..7
  const int gid = blockIdx.x & 3;          // batch group
  const int mem = blockIdx.x >> 2;         // member within group
  const int b0 = gid * BROWS;
  const int j0 = mem * JCH;

  // ---- per-thread gate-phase constants (thread <-> (row, j) fixed) ----
  const int grow = tid >> 5;               // local batch row 0..15
  const int gj = tid & 31;                 // local hidden 0..31
  const float br = bih[j0 + gj] + bhh[j0 + gj];
  const float bz = bih[512 + j0 + gj] + bhh[512 + j0 + gj];
  const float bi_n = bih[1024 + j0 + gj];
  const float bh_n = bhh[1024 + j0 + gj];
  float hprev = h0[(size_t)(b0 + grow) * HD + j0 + gj];   // f32 running state in-register
  const int lenr = lens[b0 + grow];        // int32 per harness integer convention
  float* const outp = out + (size_t)(b0 + grow) * Tsz * HD + j0 + gj;  // + t*HD per step

  // ---- poll-phase constants: thread polls one 64B line (8 u64 = 16 h cols) ----
  const int prow = tid >> 5;               // local batch row 0..15
  const int pcu = (tid & 31) * 8;          // first u64 (col-pair) index in row
  const uint64_t* psrc = hbx + (size_t)(b0 + prow) * 256 + pcu;

  // ---- x staging constants: c4 fixed per thread, 4 rows at stride 4 ----
  const int xc4 = tid & 127;
  const int xr0 = tid >> 7;                // rows xr0, xr0+4, xr0+8, xr0+12
  const float* xb[4];
  uint32_t* xdst_off[1];  // (unused placeholder to keep style minimal)
#pragma unroll
  for (int i = 0; i < 4; ++i)
    xb[i] = x + (size_t)(b0 + xr0 + 4 * i) * Tsz * HD + xc4 * 4;

  // ---- stationary weight fragments (held in VGPRs for the whole scan) ----
  const int c = lane & 15;                 // MFMA col (gate) / A-row (batch)
  const int kg = lane >> 4;                // k-group 0..3
  bf16x8 wfa[16], wfb[16];
  if (wv < 4) {                            // combined r/z: wv0,1 = r cols, wv2,3 = z cols
    const int wrow = (wv >> 1) * 512 + j0 + (wv & 1) * 16 + c;
#pragma unroll
    for (int ks = 0; ks < 16; ++ks) {
      const int k0 = ks * 32 + kg * 8;
      wfa[ks] = ldwf(Wih, wrow, k0);
      wfb[ks] = ldwf(Whh, wrow, k0);
    }
  } else if (wv < 6) {                     // i_n
    const int wrow = 1024 + j0 + (wv - 4) * 16 + c;
#pragma unroll
    for (int ks = 0; ks < 16; ++ks) wfa[ks] = ldwf(Wih, wrow, ks * 32 + kg * 8);
  } else {                                 // h_n
    const int wrow = 1024 + j0 + (wv - 6) * 16 + c;
#pragma unroll
    for (int ks = 0; ks < 16; ++ks) wfb[ks] = ldwf(Whh, wrow, ks * 32 + kg * 8);
  }

  stage_x0(x, b0, (uint32_t*)&x_lds[0][0], tid);   // prologue: x(0) -> LDS parity 0

  // Deep prefetch of x(1) into registers (consumed by the staging phase of t=0).
  f32x4 xr[4];
#pragma unroll
  for (int i = 0; i < 4; ++i)
    xr[i] = *reinterpret_cast<const f32x4*>(xb[i] + (size_t)1 * HD);

  float o_pend = 0.f;                      // deferred out[] value for step t-1

  for (int t = 0; t < Tsz; ++t) {
    // ---- phase A2: poll tagged h(t-1); only the hbx packet store ack (whose
    //      latency IS the exchange flight) is outstanding here ----
    {
      const uint64_t* src = psrc + (size_t)((t + 1) & 1) * HSLOT;
      const uint32_t want = (uint32_t)t;   // tag of h(t-1)
      uint64_t v[8];
      for (;;) {
        bool ok = true;
#pragma unroll
        for (int i = 0; i < 8; ++i)
          v[i] = __hip_atomic_load(src + i, __ATOMIC_RELAXED, __HIP_MEMORY_SCOPE_AGENT);
#pragma unroll
        for (int i = 0; i < 8; ++i) ok &= ((uint32_t)(v[i] >> 32) == want);
        if (ok) break;
      }
      uint32_t* dst = (uint32_t*)&h_lds[0] + prow * LROWD + pcu;
      u32x4 w0 = {(uint32_t)v[0], (uint32_t)v[1], (uint32_t)v[2], (uint32_t)v[3]};
      u32x4 w1 = {(uint32_t)v[4], (uint32_t)v[5], (uint32_t)v[6], (uint32_t)v[7]};
      *reinterpret_cast<u32x4*>(dst) = w0;
      *reinterpret_cast<u32x4*>(dst + 4) = w1;
    }

    // ---- deferred out store for step t-1: its HBM ack retires under the MFMA
    //      and gate phases instead of in front of the next poll ----
    if (t > 0) outp[(size_t)(t - 1) * HD] = o_pend;

    // ---- phase A3: convert prefetched x(t+1) registers -> LDS ----
    if (t + 1 < Tsz) {
      uint32_t* xl = (uint32_t*)&x_lds[(t + 1) & 1][0];
#pragma unroll
      for (int i = 0; i < 4; ++i) {
        u32x2 w;
        w.x = f2bf(xr[i].x) | (f2bf(xr[i].y) << 16);
        w.y = f2bf(xr[i].z) | (f2bf(xr[i].w) << 16);
        *reinterpret_cast<u32x2*>(xl + (xr0 + 4 * i) * LROWD + xc4 * 2) = w;
      }
    }

    // ---- deep prefetch x(t+2): issued pre-barrier so its HBM latency is covered
    //      by MFMA + gates; retired long before the next poll's vmcnt wait ----
    if (t + 2 < Tsz) {
#pragma unroll
      for (int i = 0; i < 4; ++i)
        xr[i] = *reinterpret_cast<const f32x4*>(xb[i] + (size_t)(t + 2) * HD);
    }

    BAR();   // S1: h_lds + x_lds(t+1) ready (lgkm only; no vmcnt drain)

    // ---- phase B: MFMA (weights stationary in registers) ----
    {
      f32x4 acc0 = {0.f, 0.f, 0.f, 0.f}, acc1 = {0.f, 0.f, 0.f, 0.f};
      const unsigned short* xl = &x_lds[t & 1][0];
      const unsigned short* hl = &h_lds[0];
      if (wv < 4) {
#pragma unroll
        for (int ks = 0; ks < 16; ks += 2) {
          bf16x8 a0 = *reinterpret_cast<const bf16x8*>(xl + c * LROW + ks * 32 + kg * 8);
          bf16x8 a1 = *reinterpret_cast<const bf16x8*>(xl + c * LROW + (ks + 1) * 32 + kg * 8);
          acc0 = __builtin_amdgcn_mfma_f32_16x16x32_bf16(a0, wfa[ks], acc0, 0, 0, 0);
          acc1 = __builtin_amdgcn_mfma_f32_16x16x32_bf16(a1, wfa[ks + 1], acc1, 0, 0, 0);
        }
#pragma unroll
        for (int ks = 0; ks < 16; ks += 2) {
          bf16x8 a0 = *reinterpret_cast<const bf16x8*>(hl + c * LROW + ks * 32 + kg * 8);
          bf16x8 a1 = *reinterpret_cast<const bf16x8*>(hl + c * LROW + (ks + 1) * 32 + kg * 8);
          acc0 = __builtin_amdgcn_mfma_f32_16x16x32_bf16(a0, wfb[ks], acc0, 0, 0, 0);
          acc1 = __builtin_amdgcn_mfma_f32_16x16x32_bf16(a1, wfb[ks + 1], acc1, 0, 0, 0);
        }
      } else if (wv < 6) {
#pragma unroll
        for (int ks = 0; ks < 16; ks += 2) {
          bf16x8 a0 = *reinterpret_cast<const bf16x8*>(xl + c * LROW + ks * 32 + kg * 8);
          bf16x8 a1 = *reinterpret_cast<const bf16x8*>(xl + c * LROW + (ks + 1) * 32 + kg * 8);
          acc0 = __builtin_amdgcn_mfma_f32_16x16x32_bf16(a0, wfa[ks], acc0, 0, 0, 0);
          acc1 = __builtin_amdgcn_mfma_f32_16x16x32_bf16(a1, wfa[ks + 1], acc1, 0, 0, 0);
        }
      } else {
#pragma unroll
        for (int ks = 0; ks < 16; ks += 2) {
          bf16x8 a0 = *reinterpret_cast<const bf16x8*>(hl + c * LROW + ks * 32 + kg * 8);
          bf16x8 a1 = *reinterpret_cast<const bf16x8*>(hl + c * LROW + (ks + 1) * 32 + kg * 8);
          acc0 = __builtin_amdgcn_mfma_f32_16x16x32_bf16(a0, wfb[ks], acc0, 0, 0, 0);
          acc1 = __builtin_amdgcn_mfma_f32_16x16x32_bf16(a1, wfb[ks + 1], acc1, 0, 0, 0);
        }
      }
      const f32x4 acc = acc0 + acc1;
      const int slot = (wv < 4) ? (wv >> 1) : ((wv < 6) ? 2 : 3);
      const int col = (wv & 1) * 16 + c;
#pragma unroll
      for (int q = 0; q < 4; ++q) s_lds[kg * 4 + q][slot][col] = acc[q];
    }
    BAR();   // S2: s_lds ready (lgkm only)

    // ---- phase C: gates, tagged h broadcast FIRST, then bookkeeping ----
    {
      const float sr = s_lds[grow][0][gj] + br;
      const float sz = s_lds[grow][1][gj] + bz;
      const float si = s_lds[grow][2][gj] + bi_n;
      const float sh = s_lds[grow][3][gj] + bh_n;
      const float r = 1.f / (1.f + __expf(-sr));
      const float z = 1.f / (1.f + __expf(-sz));
      const float n = tanhf(si + r * sh);
      const float hnew = (1.f - z) * n + z * hprev;
      const bool m = (t < lenr);
      const float hk = m ? hnew : hprev;
      const uint32_t ub = f2bf(hk);
      const uint32_t ot = __shfl_xor(ub, 1);
      if ((t + 1 < Tsz) && ((lane & 1) == 0)) {
        const uint32_t word = ub | (ot << 16);
        const uint64_t pkt = ((uint64_t)(uint32_t)(t + 1) << 32) | (uint64_t)word;
        __hip_atomic_store(hbx + (size_t)(t & 1) * HSLOT + (size_t)(b0 + grow) * 256 +
                               ((j0 + gj) >> 1),
                           pkt, __ATOMIC_RELAXED, __HIP_MEMORY_SCOPE_AGENT);
      }
      o_pend = m ? hnew : 0.f;
      hprev = hk;
    }
    // no end-of-step barrier: the tagged dataflow exchange self-synchronizes members;
    // S1's collectivity protects all intra-WG LDS buffer reuse across steps.
  }

  // epilogue: last step's deferred output + final state
  outp[(size_t)(Tsz - 1) * HD] = o_pend;
  outh[(size_t)(b0 + grow) * HD + j0 + gj] = hprev;
}

extern "C" void kernel_launch(void* const* d_in, const int* in_sizes, int n_in,
                              void* d_out, int out_size, void* d_ws, size_t ws_size,
                              hipStream_t stream) {
  const float* x = (const float*)d_in[0];
  const float* h0 = (const float*)d_in[1];
  const float* Wih = (const float*)d_in[2];
  const float* Whh = (const float*)d_in[3];
  const float* bih = (const float*)d_in[4];
  const float* bhh = (const float*)d_in[5];
  const int* lens = (const int*)d_in[6];
  float* out = (float*)d_out;
  float* outh = out + (size_t)Bsz * Tsz * HD;

  uint64_t* hbx = (uint64_t*)d_ws;                 // [2][Bsz][HD/2] tagged bf16 pairs, 256 KB

  gru_init<<<64, 256, 0, stream>>>(h0, hbx);
  gru_persist<<<NWG, NTHR, 0, stream>>>(x, h0, Wih, Whh, bih, bhh, lens,
                                        out, outh, hbx);
}

// Round 3
// 1749.131 us; speedup vs baseline: 1.2636x; 1.2636x over previous
//
#include <hip/hip_runtime.h>
#include <stdint.h>

#define Bsz 64
#define Tsz 512
#define HD  512
#define GROUPS 4
#define MEMBERS 16
#define BROWS 16          // batch rows per group
#define JCH 32            // hidden units per workgroup
#define NWG (GROUPS*MEMBERS)
#define NTHR 512
#define LROW 520          // LDS row stride in halfwords (512 + 8 pad)
#define LROWD 260         // same in dwords
#define HSLOT (Bsz*HD/2)  // 16384 u64 per parity buffer

typedef __attribute__((ext_vector_type(8))) short bf16x8;
typedef __attribute__((ext_vector_type(4))) float f32x4;
typedef __attribute__((ext_vector_type(4))) uint32_t u32x4;
typedef __attribute__((ext_vector_type(2))) uint32_t u32x2;

__device__ __forceinline__ uint32_t f2bf(float f) {
  uint32_t u = __builtin_bit_cast(uint32_t, f);
  return (u + 0x7FFFu + ((u >> 16) & 1u)) >> 16;   // RNE f32 -> bf16
}

// Load 8 consecutive f32 from W[row][k0..k0+7], convert to a bf16x8 MFMA B-fragment.
__device__ __forceinline__ bf16x8 ldwf(const float* __restrict__ W, int row, int k0) {
  const f32x4 a = *reinterpret_cast<const f32x4*>(W + (size_t)row * HD + k0);
  const f32x4 b = *reinterpret_cast<const f32x4*>(W + (size_t)row * HD + k0 + 4);
  bf16x8 r;
  r[0] = (short)f2bf(a.x); r[1] = (short)f2bf(a.y);
  r[2] = (short)f2bf(a.z); r[3] = (short)f2bf(a.w);
  r[4] = (short)f2bf(b.x); r[5] = (short)f2bf(b.y);
  r[6] = (short)f2bf(b.z); r[7] = (short)f2bf(b.w);
  return r;
}

// Stage x[b0..b0+15][t][:] (f32) into LDS as bf16, rows padded to LROW halfwords.
__device__ __forceinline__ void stage_x(const float* __restrict__ x, int t, int b0,
                                        uint32_t* xl, int tid) {
#pragma unroll
  for (int i = 0; i < 4; ++i) {
    const int fl = tid + i * 512;        // float4 index over 16x128
    const int row = fl >> 7;
    const int c4 = fl & 127;
    const f32x4 v = *reinterpret_cast<const f32x4*>(
        x + ((size_t)(b0 + row) * Tsz + t) * HD + c4 * 4);
    u32x2 w;
    w.x = f2bf(v.x) | (f2bf(v.y) << 16);
    w.y = f2bf(v.z) | (f2bf(v.w) << 16);
    *reinterpret_cast<u32x2*>(xl + row * LROWD + c4 * 2) = w;
  }
}

// Exchange buffer hbx: u64[2][Bsz][256]. Each u64 = (tag << 32) | (2 packed bf16).
// h(s) lives at parity s&1 with tag s+1; h(-1)=h0 at parity 1 with tag 0.
__global__ void gru_init(const float* __restrict__ h0, uint64_t* __restrict__ hbx) {
  const int i = blockIdx.x * 256 + threadIdx.x;
  if (i < HSLOT) {
    const float a = h0[2 * i], b = h0[2 * i + 1];
    hbx[HSLOT + i] = (uint64_t)(f2bf(a) | (f2bf(b) << 16));  // parity 1: tag 0 | h0
    hbx[i] = 0xFFFFFFFF00000000ull;                          // parity 0: never-matching tag
  }
}

__global__ void __launch_bounds__(NTHR) gru_persist(
    const float* __restrict__ x, const float* __restrict__ h0,
    const float* __restrict__ Wih, const float* __restrict__ Whh,
    const float* __restrict__ bih, const float* __restrict__ bhh,
    const int* __restrict__ lens,
    float* __restrict__ out, float* __restrict__ outh,
    uint64_t* __restrict__ hbx) {
  __shared__ alignas(16) unsigned short x_lds[2][BROWS * LROW];
  __shared__ alignas(16) unsigned short h_lds[BROWS * LROW];
  __shared__ alignas(16) float s_lds[BROWS][4][JCH];   // [row][r,z,i_n,h_n][j]

  const int tid = threadIdx.x;
  const int lane = tid & 63;
  const int wv = tid >> 6;                 // wave 0..7
  const int gid = blockIdx.x & 3;          // batch group
  const int mem = blockIdx.x >> 2;         // member within group
  const int b0 = gid * BROWS;
  const int j0 = mem * JCH;

  // ---- per-thread gate-phase constants (thread <-> (row, j) fixed) ----
  const int grow = tid >> 5;               // local batch row 0..15
  const int gj = tid & 31;                 // local hidden 0..31
  const float br = bih[j0 + gj] + bhh[j0 + gj];
  const float bz = bih[512 + j0 + gj] + bhh[512 + j0 + gj];
  const float bi_n = bih[1024 + j0 + gj];
  const float bh_n = bhh[1024 + j0 + gj];
  float hprev = h0[(size_t)(b0 + grow) * HD + j0 + gj];   // f32 running state in-register
  const int lenr = lens[b0 + grow];        // int32 per harness integer convention

  // ---- poll-phase constants: thread owns one 64B line (8 u64 = 16 h cols) ----
  const int prow = tid >> 5;               // local batch row 0..15
  const int pcu = (tid & 31) * 8;          // first u64 (col-pair) index in row
  const uint64_t* psrc = hbx + (size_t)(b0 + prow) * 256 + pcu;

  // ---- stationary weight fragments (held in VGPRs for the whole scan) ----
  const int c = lane & 15;                 // MFMA col (gate) / A-row (batch)
  const int kg = lane >> 4;                // k-group 0..3
  bf16x8 wfa[16], wfb[16];
  if (wv < 4) {                            // combined r/z: wv0,1 = r cols, wv2,3 = z cols
    const int wrow = (wv >> 1) * 512 + j0 + (wv & 1) * 16 + c;
#pragma unroll
    for (int ks = 0; ks < 16; ++ks) {
      const int k0 = ks * 32 + kg * 8;
      wfa[ks] = ldwf(Wih, wrow, k0);
      wfb[ks] = ldwf(Whh, wrow, k0);
    }
  } else if (wv < 6) {                     // i_n
    const int wrow = 1024 + j0 + (wv - 4) * 16 + c;
#pragma unroll
    for (int ks = 0; ks < 16; ++ks) wfa[ks] = ldwf(Wih, wrow, ks * 32 + kg * 8);
  } else {                                 // h_n
    const int wrow = 1024 + j0 + (wv - 6) * 16 + c;
#pragma unroll
    for (int ks = 0; ks < 16; ++ks) wfb[ks] = ldwf(Whh, wrow, ks * 32 + kg * 8);
  }

  stage_x(x, 0, b0, (uint32_t*)&x_lds[0][0], tid);   // prologue

  for (int t = 0; t < Tsz; ++t) {
    // ---- phase A1: issue x(t+1) loads early; latency hides under the poll ----
    f32x4 xr[4];
    if (t + 1 < Tsz) {
#pragma unroll
      for (int i = 0; i < 4; ++i) {
        const int fl = tid + i * 512;
        const int row = fl >> 7;
        const int c4 = fl & 127;
        xr[i] = *reinterpret_cast<const f32x4*>(
            x + ((size_t)(b0 + row) * Tsz + (t + 1)) * HD + c4 * 4);
      }
    }

    // ---- phase A2: sentinel-first poll of tagged h(t-1) ----
    // All 8 u64 of this thread's line are stored back-to-back by one producer,
    // so spin on ONE u64 (1/8th the fabric traffic of polling all 8), then
    // bulk-load + tag-verify the rest (retry preserves correctness).
    {
      const uint64_t* src = psrc + (size_t)((t + 1) & 1) * HSLOT;
      const uint32_t want = (uint32_t)t;   // tag of h(t-1)
      uint64_t v[8];
      uint64_t s0;
      do {
        s0 = __hip_atomic_load(src, __ATOMIC_RELAXED, __HIP_MEMORY_SCOPE_AGENT);
      } while ((uint32_t)(s0 >> 32) != want);
      v[0] = s0;
      for (;;) {
        bool ok = true;
#pragma unroll
        for (int i = 1; i < 8; ++i)
          v[i] = __hip_atomic_load(src + i, __ATOMIC_RELAXED, __HIP_MEMORY_SCOPE_AGENT);
#pragma unroll
        for (int i = 1; i < 8; ++i) ok &= ((uint32_t)(v[i] >> 32) == want);
        if (ok) break;
      }
      uint32_t* dst = (uint32_t*)&h_lds[0] + prow * LROWD + pcu;
      u32x4 w0 = {(uint32_t)v[0], (uint32_t)v[1], (uint32_t)v[2], (uint32_t)v[3]};
      u32x4 w1 = {(uint32_t)v[4], (uint32_t)v[5], (uint32_t)v[6], (uint32_t)v[7]};
      *reinterpret_cast<u32x4*>(dst) = w0;
      *reinterpret_cast<u32x4*>(dst + 4) = w1;
    }

    // ---- phase A3: convert + write staged x(t+1) (loads have landed by now) ----
    if (t + 1 < Tsz) {
      uint32_t* xl = (uint32_t*)&x_lds[(t + 1) & 1][0];
#pragma unroll
      for (int i = 0; i < 4; ++i) {
        const int fl = tid + i * 512;
        const int row = fl >> 7;
        const int c4 = fl & 127;
        u32x2 w;
        w.x = f2bf(xr[i].x) | (f2bf(xr[i].y) << 16);
        w.y = f2bf(xr[i].z) | (f2bf(xr[i].w) << 16);
        *reinterpret_cast<u32x2*>(xl + row * LROWD + c4 * 2) = w;
      }
    }
    __syncthreads();   // S1: h_lds + x_lds(t+1) ready

    // ---- phase B: MFMA (weights stationary in registers) ----
    {
      f32x4 acc0 = {0.f, 0.f, 0.f, 0.f}, acc1 = {0.f, 0.f, 0.f, 0.f};
      const unsigned short* xl = &x_lds[t & 1][0];
      const unsigned short* hl = &h_lds[0];
      if (wv < 4) {
#pragma unroll
        for (int ks = 0; ks < 16; ks += 2) {
          bf16x8 a0 = *reinterpret_cast<const bf16x8*>(xl + c * LROW + ks * 32 + kg * 8);
          bf16x8 a1 = *reinterpret_cast<const bf16x8*>(xl + c * LROW + (ks + 1) * 32 + kg * 8);
          acc0 = __builtin_amdgcn_mfma_f32_16x16x32_bf16(a0, wfa[ks], acc0, 0, 0, 0);
          acc1 = __builtin_amdgcn_mfma_f32_16x16x32_bf16(a1, wfa[ks + 1], acc1, 0, 0, 0);
        }
#pragma unroll
        for (int ks = 0; ks < 16; ks += 2) {
          bf16x8 a0 = *reinterpret_cast<const bf16x8*>(hl + c * LROW + ks * 32 + kg * 8);
          bf16x8 a1 = *reinterpret_cast<const bf16x8*>(hl + c * LROW + (ks + 1) * 32 + kg * 8);
          acc0 = __builtin_amdgcn_mfma_f32_16x16x32_bf16(a0, wfb[ks], acc0, 0, 0, 0);
          acc1 = __builtin_amdgcn_mfma_f32_16x16x32_bf16(a1, wfb[ks + 1], acc1, 0, 0, 0);
        }
      } else if (wv < 6) {
#pragma unroll
        for (int ks = 0; ks < 16; ks += 2) {
          bf16x8 a0 = *reinterpret_cast<const bf16x8*>(xl + c * LROW + ks * 32 + kg * 8);
          bf16x8 a1 = *reinterpret_cast<const bf16x8*>(xl + c * LROW + (ks + 1) * 32 + kg * 8);
          acc0 = __builtin_amdgcn_mfma_f32_16x16x32_bf16(a0, wfa[ks], acc0, 0, 0, 0);
          acc1 = __builtin_amdgcn_mfma_f32_16x16x32_bf16(a1, wfa[ks + 1], acc1, 0, 0, 0);
        }
      } else {
#pragma unroll
        for (int ks = 0; ks < 16; ks += 2) {
          bf16x8 a0 = *reinterpret_cast<const bf16x8*>(hl + c * LROW + ks * 32 + kg * 8);
          bf16x8 a1 = *reinterpret_cast<const bf16x8*>(hl + c * LROW + (ks + 1) * 32 + kg * 8);
          acc0 = __builtin_amdgcn_mfma_f32_16x16x32_bf16(a0, wfb[ks], acc0, 0, 0, 0);
          acc1 = __builtin_amdgcn_mfma_f32_16x16x32_bf16(a1, wfb[ks + 1], acc1, 0, 0, 0);
        }
      }
      const f32x4 acc = acc0 + acc1;
      const int slot = (wv < 4) ? (wv >> 1) : ((wv < 6) ? 2 : 3);
      const int col = (wv & 1) * 16 + c;
#pragma unroll
      for (int q = 0; q < 4; ++q) s_lds[kg * 4 + q][slot][col] = acc[q];
    }
    __syncthreads();   // S2: s_lds ready

    // ---- phase C: gates (1 element per thread); hbx packet store issued FIRST
    //      (in-order VMEM queue: exchange flight starts before the out store) ----
    {
      const float sr = s_lds[grow][0][gj] + br;
      const float sz = s_lds[grow][1][gj] + bz;
      const float si = s_lds[grow][2][gj] + bi_n;
      const float sh = s_lds[grow][3][gj] + bh_n;
      const float r = 1.f / (1.f + __expf(-sr));
      const float z = 1.f / (1.f + __expf(-sz));
      const float n = tanhf(si + r * sh);
      const float hnew = (1.f - z) * n + z * hprev;
      const bool m = (t < lenr);
      const float hk = m ? hnew : hprev;
      const uint32_t ub = f2bf(hk);
      const uint32_t ot = __shfl_xor(ub, 1);
      if ((t + 1 < Tsz) && ((lane & 1) == 0)) {
        const uint32_t word = ub | (ot << 16);
        const uint64_t pkt = ((uint64_t)(uint32_t)(t + 1) << 32) | (uint64_t)word;
        __hip_atomic_store(hbx + (size_t)(t & 1) * HSLOT + (size_t)(b0 + grow) * 256 +
                               ((j0 + gj) >> 1),
                           pkt, __ATOMIC_RELAXED, __HIP_MEMORY_SCOPE_AGENT);
      }
      out[((size_t)(b0 + grow) * Tsz + t) * HD + j0 + gj] = m ? hnew : 0.f;
      hprev = hk;
      if (t == Tsz - 1) outh[(size_t)(b0 + grow) * HD + j0 + gj] = hk;
    }
    // no end-of-step barrier: the tagged dataflow exchange self-synchronizes members;
    // S1's collectivity protects all intra-WG LDS buffer reuse across steps.
  }
}

extern "C" void kernel_launch(void* const* d_in, const int* in_sizes, int n_in,
                              void* d_out, int out_size, void* d_ws, size_t ws_size,
                              hipStream_t stream) {
  const float* x = (const float*)d_in[0];
  const float* h0 = (const float*)d_in[1];
  const float* Wih = (const float*)d_in[2];
  const float* Whh = (const float*)d_in[3];
  const float* bih = (const float*)d_in[4];
  const float* bhh = (const float*)d_in[5];
  const int* lens = (const int*)d_in[6];
  float* out = (float*)d_out;
  float* outh = out + (size_t)Bsz * Tsz * HD;

  uint64_t* hbx = (uint64_t*)d_ws;                 // [2][Bsz][HD/2] tagged bf16 pairs, 256 KB

  gru_init<<<64, 256, 0, stream>>>(h0, hbx);
  gru_persist<<<NWG, NTHR, 0, stream>>>(x, h0, Wih, Whh, bih, bhh, lens,
                                        out, outh, hbx);
}

// Round 4
// 1471.502 us; speedup vs baseline: 1.5020x; 1.1887x over previous
//
#include <hip/hip_runtime.h>
#include <stdint.h>

#define Bsz 64
#define Tsz 512
#define HD  512
#define GROUPS 4
#define MEMBERS 16
#define BROWS 16          // batch rows per group
#define JCH 32            // hidden units per workgroup
#define NWG (GROUPS*MEMBERS)
#define NTHR 512
#define LROW 520          // LDS row stride in halfwords (512 + 8 pad)
#define LROWD 260         // same in dwords
#define HSLOT (Bsz*HD/2)  // 16384 u64 per parity buffer

typedef __attribute__((ext_vector_type(8))) short bf16x8;
typedef __attribute__((ext_vector_type(4))) float f32x4;
typedef __attribute__((ext_vector_type(4))) uint32_t u32x4;
typedef __attribute__((ext_vector_type(2))) uint32_t u32x2;

__device__ __forceinline__ uint32_t f2bf(float f) {
  uint32_t u = __builtin_bit_cast(uint32_t, f);
  return (u + 0x7FFFu + ((u >> 16) & 1u)) >> 16;   // RNE f32 -> bf16
}

// Load 8 consecutive f32 from W[row][k0..k0+7], convert to a bf16x8 MFMA B-fragment.
__device__ __forceinline__ bf16x8 ldwf(const float* __restrict__ W, int row, int k0) {
  const f32x4 a = *reinterpret_cast<const f32x4*>(W + (size_t)row * HD + k0);
  const f32x4 b = *reinterpret_cast<const f32x4*>(W + (size_t)row * HD + k0 + 4);
  bf16x8 r;
  r[0] = (short)f2bf(a.x); r[1] = (short)f2bf(a.y);
  r[2] = (short)f2bf(a.z); r[3] = (short)f2bf(a.w);
  r[4] = (short)f2bf(b.x); r[5] = (short)f2bf(b.y);
  r[6] = (short)f2bf(b.z); r[7] = (short)f2bf(b.w);
  return r;
}

// Prologue-only: stage x[b0..b0+15][0][:] (f32) into LDS as bf16.
__device__ __forceinline__ void stage_x0(const float* __restrict__ x, int b0,
                                         uint32_t* xl, int tid) {
#pragma unroll
  for (int i = 0; i < 4; ++i) {
    const int fl = tid + i * 512;        // float4 index over 16x128
    const int row = fl >> 7;
    const int c4 = fl & 127;
    const f32x4 v = *reinterpret_cast<const f32x4*>(
        x + (size_t)(b0 + row) * Tsz * HD + c4 * 4);
    u32x2 w;
    w.x = f2bf(v.x) | (f2bf(v.y) << 16);
    w.y = f2bf(v.z) | (f2bf(v.w) << 16);
    *reinterpret_cast<u32x2*>(xl + row * LROWD + c4 * 2) = w;
  }
}

// Exchange buffer hbx: u64[2][Bsz][256]. Each u64 = (tag << 32) | (2 packed bf16).
// h(s) lives at parity s&1 with tag s+1; h(-1)=h0 at parity 1 with tag 0.
__global__ void gru_init(const float* __restrict__ h0, uint64_t* __restrict__ hbx) {
  const int i = blockIdx.x * 256 + threadIdx.x;
  if (i < HSLOT) {
    const float a = h0[2 * i], b = h0[2 * i + 1];
    hbx[HSLOT + i] = (uint64_t)(f2bf(a) | (f2bf(b) << 16));  // parity 1: tag 0 | h0
    hbx[i] = 0xFFFFFFFF00000000ull;                          // parity 0: never-matching tag
  }
}

__global__ void __launch_bounds__(NTHR) gru_persist(
    const float* __restrict__ x, const float* __restrict__ h0,
    const float* __restrict__ Wih, const float* __restrict__ Whh,
    const float* __restrict__ bih, const float* __restrict__ bhh,
    const int* __restrict__ lens,
    float* __restrict__ out, float* __restrict__ outh,
    uint64_t* __restrict__ hbx) {
  __shared__ alignas(16) unsigned short x_lds[2][BROWS * LROW];
  __shared__ alignas(16) unsigned short h_lds[BROWS * LROW];
  __shared__ alignas(16) float s_lds[BROWS][4][JCH];   // [row][r,z,i_n,h_n][j]

  const int tid = threadIdx.x;
  const int lane = tid & 63;
  const int wv = tid >> 6;                 // wave 0..7
  const int gid = blockIdx.x & 3;          // batch group
  const int mem = blockIdx.x >> 2;         // member within group
  const int b0 = gid * BROWS;
  const int j0 = mem * JCH;

  // ---- per-thread gate-phase constants (thread <-> (row, j) fixed) ----
  const int grow = tid >> 5;               // local batch row 0..15
  const int gj = tid & 31;                 // local hidden 0..31
  const float br = bih[j0 + gj] + bhh[j0 + gj];
  const float bz = bih[512 + j0 + gj] + bhh[512 + j0 + gj];
  const float bi_n = bih[1024 + j0 + gj];
  const float bh_n = bhh[1024 + j0 + gj];
  float hprev = h0[(size_t)(b0 + grow) * HD + j0 + gj];   // f32 running state in-register
  const int lenr = lens[b0 + grow];        // int32 per harness integer convention

  // ---- poll-phase constants: thread owns one 64B line (8 u64 = 16 h cols) ----
  const int prow = tid >> 5;               // local batch row 0..15
  const int pcu = (tid & 31) * 8;          // first u64 (col-pair) index in row
  const uint64_t* psrc = hbx + (size_t)(b0 + prow) * 256 + pcu;

  // ---- x prefetch constants (thread owns fixed (row stride-4, c4) pattern) ----
  const int xc4 = tid & 127;
  const int xr0 = tid >> 7;                // rows xr0, xr0+4, xr0+8, xr0+12
  const float* xbp[4];
#pragma unroll
  for (int i = 0; i < 4; ++i)
    xbp[i] = x + (size_t)(b0 + xr0 + 4 * i) * Tsz * HD + xc4 * 4;

  // ---- stationary weight fragments (held in VGPRs for the whole scan) ----
  const int c = lane & 15;                 // MFMA col (gate) / A-row (batch)
  const int kg = lane >> 4;                // k-group 0..3
  bf16x8 wfa[16], wfb[16];
  if (wv < 4) {                            // combined r/z: wv0,1 = r cols, wv2,3 = z cols
    const int wrow = (wv >> 1) * 512 + j0 + (wv & 1) * 16 + c;
#pragma unroll
    for (int ks = 0; ks < 16; ++ks) {
      const int k0 = ks * 32 + kg * 8;
      wfa[ks] = ldwf(Wih, wrow, k0);
      wfb[ks] = ldwf(Whh, wrow, k0);
    }
  } else if (wv < 6) {                     // i_n (x-part only)
    const int wrow = 1024 + j0 + (wv - 4) * 16 + c;
#pragma unroll
    for (int ks = 0; ks < 16; ++ks) wfa[ks] = ldwf(Wih, wrow, ks * 32 + kg * 8);
  } else {                                 // h_n (h-part only)
    const int wrow = 1024 + j0 + (wv - 6) * 16 + c;
#pragma unroll
    for (int ks = 0; ks < 16; ++ks) wfb[ks] = ldwf(Whh, wrow, ks * 32 + kg * 8);
  }

  stage_x0(x, b0, (uint32_t*)&x_lds[0][0], tid);   // prologue: x(0) -> parity 0

  // prologue prefetch: x(1) -> registers (consumed at t=0's A3)
  f32x4 xr[4];
#pragma unroll
  for (int i = 0; i < 4; ++i)
    xr[i] = *reinterpret_cast<const f32x4*>(xbp[i] + (size_t)1 * HD);

  __syncthreads();   // prologue staging visible to all waves before t=0 P0

  for (int t = 0; t < Tsz; ++t) {
    // ---- P0: x-part MFMAs (need no h(t-1)); overlaps the store-ack drain and
    //      producer-visibility window of the poll below ----
    f32x4 acc0 = {0.f, 0.f, 0.f, 0.f}, acc1 = {0.f, 0.f, 0.f, 0.f};
    {
      const unsigned short* xl = &x_lds[t & 1][0];
      if (wv < 6) {
#pragma unroll
        for (int ks = 0; ks < 16; ks += 2) {
          bf16x8 a0 = *reinterpret_cast<const bf16x8*>(xl + c * LROW + ks * 32 + kg * 8);
          bf16x8 a1 = *reinterpret_cast<const bf16x8*>(xl + c * LROW + (ks + 1) * 32 + kg * 8);
          acc0 = __builtin_amdgcn_mfma_f32_16x16x32_bf16(a0, wfa[ks], acc0, 0, 0, 0);
          acc1 = __builtin_amdgcn_mfma_f32_16x16x32_bf16(a1, wfa[ks + 1], acc1, 0, 0, 0);
        }
      }
    }

    // ---- A2: sentinel-first poll of tagged h(t-1). No x loads were issued this
    //      step before the poll, so the in-order vmcnt drain only covers the
    //      (long-retired) depth-2 prefetch and last step's stores ----
    {
      const uint64_t* src = psrc + (size_t)((t + 1) & 1) * HSLOT;
      const uint32_t want = (uint32_t)t;   // tag of h(t-1)
      uint64_t v[8];
      uint64_t s0;
      do {
        s0 = __hip_atomic_load(src, __ATOMIC_RELAXED, __HIP_MEMORY_SCOPE_AGENT);
      } while ((uint32_t)(s0 >> 32) != want);
      v[0] = s0;
      for (;;) {
        bool ok = true;
#pragma unroll
        for (int i = 1; i < 8; ++i)
          v[i] = __hip_atomic_load(src + i, __ATOMIC_RELAXED, __HIP_MEMORY_SCOPE_AGENT);
#pragma unroll
        for (int i = 1; i < 8; ++i) ok &= ((uint32_t)(v[i] >> 32) == want);
        if (ok) break;
      }
      uint32_t* dst = (uint32_t*)&h_lds[0] + prow * LROWD + pcu;
      u32x4 w0 = {(uint32_t)v[0], (uint32_t)v[1], (uint32_t)v[2], (uint32_t)v[3]};
      u32x4 w1 = {(uint32_t)v[4], (uint32_t)v[5], (uint32_t)v[6], (uint32_t)v[7]};
      *reinterpret_cast<u32x4*>(dst) = w0;
      *reinterpret_cast<u32x4*>(dst + 4) = w1;
    }

    // ---- A3: convert prefetched x(t+1) -> LDS (opposite buffer from P0's) ----
    if (t + 1 < Tsz) {
      uint32_t* xl = (uint32_t*)&x_lds[(t + 1) & 1][0];
#pragma unroll
      for (int i = 0; i < 4; ++i) {
        u32x2 w;
        w.x = f2bf(xr[i].x) | (f2bf(xr[i].y) << 16);
        w.y = f2bf(xr[i].z) | (f2bf(xr[i].w) << 16);
        *reinterpret_cast<u32x2*>(xl + (xr0 + 4 * i) * LROWD + xc4 * 2) = w;
      }
    }

    // ---- A1': issue depth-2 prefetch x(t+2); retires during B/C/next-P0, so it
    //      never sits in front of a poll check ----
    if (t + 2 < Tsz) {
#pragma unroll
      for (int i = 0; i < 4; ++i)
        xr[i] = *reinterpret_cast<const f32x4*>(xbp[i] + (size_t)(t + 2) * HD);
    }

    __syncthreads();   // S1: h_lds + x_lds(t+1) ready

    // ---- P2: h-part MFMAs; all s_lds writes stay post-S1 (guards C(t-1) readers) ----
    {
      const unsigned short* hl = &h_lds[0];
      if (wv < 4 || wv >= 6) {
#pragma unroll
        for (int ks = 0; ks < 16; ks += 2) {
          bf16x8 a0 = *reinterpret_cast<const bf16x8*>(hl + c * LROW + ks * 32 + kg * 8);
          bf16x8 a1 = *reinterpret_cast<const bf16x8*>(hl + c * LROW + (ks + 1) * 32 + kg * 8);
          acc0 = __builtin_amdgcn_mfma_f32_16x16x32_bf16(a0, wfb[ks], acc0, 0, 0, 0);
          acc1 = __builtin_amdgcn_mfma_f32_16x16x32_bf16(a1, wfb[ks + 1], acc1, 0, 0, 0);
        }
      }
      const f32x4 acc = acc0 + acc1;
      const int slot = (wv < 4) ? (wv >> 1) : ((wv < 6) ? 2 : 3);
      const int col = (wv & 1) * 16 + c;
#pragma unroll
      for (int q = 0; q < 4; ++q) s_lds[kg * 4 + q][slot][col] = acc[q];
    }
    __syncthreads();   // S2: s_lds ready

    // ---- C: gates; hbx packet store issued first (exchange flight starts first
    //      in the in-order VMEM queue), then the out store ----
    {
      const float sr = s_lds[grow][0][gj] + br;
      const float sz = s_lds[grow][1][gj] + bz;
      const float si = s_lds[grow][2][gj] + bi_n;
      const float sh = s_lds[grow][3][gj] + bh_n;
      const float r = 1.f / (1.f + __expf(-sr));
      const float z = 1.f / (1.f + __expf(-sz));
      const float n = tanhf(si + r * sh);
      const float hnew = (1.f - z) * n + z * hprev;
      const bool m = (t < lenr);
      const float hk = m ? hnew : hprev;
      const uint32_t ub = f2bf(hk);
      const uint32_t ot = __shfl_xor(ub, 1);
      if ((t + 1 < Tsz) && ((lane & 1) == 0)) {
        const uint32_t word = ub | (ot << 16);
        const uint64_t pkt = ((uint64_t)(uint32_t)(t + 1) << 32) | (uint64_t)word;
        __hip_atomic_store(hbx + (size_t)(t & 1) * HSLOT + (size_t)(b0 + grow) * 256 +
                               ((j0 + gj) >> 1),
                           pkt, __ATOMIC_RELAXED, __HIP_MEMORY_SCOPE_AGENT);
      }
      out[((size_t)(b0 + grow) * Tsz + t) * HD + j0 + gj] = m ? hnew : 0.f;
      hprev = hk;
      if (t == Tsz - 1) outh[(size_t)(b0 + grow) * HD + j0 + gj] = hk;
    }
    // no end-of-step barrier: the tagged dataflow exchange self-synchronizes members;
    // S1's collectivity protects all intra-WG LDS buffer reuse across steps.
  }
}

extern "C" void kernel_launch(void* const* d_in, const int* in_sizes, int n_in,
                              void* d_out, int out_size, void* d_ws, size_t ws_size,
                              hipStream_t stream) {
  const float* x = (const float*)d_in[0];
  const float* h0 = (const float*)d_in[1];
  const float* Wih = (const float*)d_in[2];
  const float* Whh = (const float*)d_in[3];
  const float* bih = (const float*)d_in[4];
  const float* bhh = (const float*)d_in[5];
  const int* lens = (const int*)d_in[6];
  float* out = (float*)d_out;
  float* outh = out + (size_t)Bsz * Tsz * HD;

  uint64_t* hbx = (uint64_t*)d_ws;                 // [2][Bsz][HD/2] tagged bf16 pairs, 256 KB

  gru_init<<<64, 256, 0, stream>>>(h0, hbx);
  gru_persist<<<NWG, NTHR, 0, stream>>>(x, h0, Wih, Whh, bih, bhh, lens,
                                        out, outh, hbx);
}

// Round 5
// 1412.969 us; speedup vs baseline: 1.5642x; 1.0414x over previous
//
#include <hip/hip_runtime.h>
#include <stdint.h>

#define Bsz 64
#define Tsz 512
#define HD  512
#define GROUPS 4
#define MEMBERS 16
#define BROWS 16          // batch rows per group
#define JCH 32            // hidden units per workgroup
#define NWG (GROUPS*MEMBERS)
#define NTHR 512
#define LROW 520          // LDS row stride in halfwords (512 + 8 pad)
#define LROWD 260         // same in dwords
#define HSLOT (Bsz*HD/2)  // 16384 u64 per parity buffer

typedef __attribute__((ext_vector_type(8))) short bf16x8;
typedef __attribute__((ext_vector_type(4))) float f32x4;
typedef __attribute__((ext_vector_type(4))) uint32_t u32x4;
typedef __attribute__((ext_vector_type(2))) uint32_t u32x2;

// lgkm-only barrier: all intra-WG LDS hazards need lgkmcnt(0)+s_barrier only.
// Deliberately does NOT drain vmcnt: the deferred out-store ack and the x
// prefetch loads stay in flight across barriers and retire under compute,
// instead of being served inside the barrier / in front of the poll.
#define BAR() asm volatile("s_waitcnt lgkmcnt(0)\n\ts_barrier" ::: "memory")

__device__ __forceinline__ uint32_t f2bf(float f) {
  uint32_t u = __builtin_bit_cast(uint32_t, f);
  return (u + 0x7FFFu + ((u >> 16) & 1u)) >> 16;   // RNE f32 -> bf16
}

// Load 8 consecutive f32 from W[row][k0..k0+7], convert to a bf16x8 MFMA B-fragment.
__device__ __forceinline__ bf16x8 ldwf(const float* __restrict__ W, int row, int k0) {
  const f32x4 a = *reinterpret_cast<const f32x4*>(W + (size_t)row * HD + k0);
  const f32x4 b = *reinterpret_cast<const f32x4*>(W + (size_t)row * HD + k0 + 4);
  bf16x8 r;
  r[0] = (short)f2bf(a.x); r[1] = (short)f2bf(a.y);
  r[2] = (short)f2bf(a.z); r[3] = (short)f2bf(a.w);
  r[4] = (short)f2bf(b.x); r[5] = (short)f2bf(b.y);
  r[6] = (short)f2bf(b.z); r[7] = (short)f2bf(b.w);
  return r;
}

// Prologue-only: stage x[b0..b0+15][0][:] (f32) into LDS as bf16.
__device__ __forceinline__ void stage_x0(const float* __restrict__ x, int b0,
                                         uint32_t* xl, int tid) {
#pragma unroll
  for (int i = 0; i < 4; ++i) {
    const int fl = tid + i * 512;        // float4 index over 16x128
    const int row = fl >> 7;
    const int c4 = fl & 127;
    const f32x4 v = *reinterpret_cast<const f32x4*>(
        x + (size_t)(b0 + row) * Tsz * HD + c4 * 4);
    u32x2 w;
    w.x = f2bf(v.x) | (f2bf(v.y) << 16);
    w.y = f2bf(v.z) | (f2bf(v.w) << 16);
    *reinterpret_cast<u32x2*>(xl + row * LROWD + c4 * 2) = w;
  }
}

// Exchange buffer hbx: u64[2][Bsz][256]. Each u64 = (tag << 32) | (2 packed bf16).
// h(s) lives at parity s&1 with tag s+1; h(-1)=h0 at parity 1 with tag 0.
__global__ void gru_init(const float* __restrict__ h0, uint64_t* __restrict__ hbx) {
  const int i = blockIdx.x * 256 + threadIdx.x;
  if (i < HSLOT) {
    const float a = h0[2 * i], b = h0[2 * i + 1];
    hbx[HSLOT + i] = (uint64_t)(f2bf(a) | (f2bf(b) << 16));  // parity 1: tag 0 | h0
    hbx[i] = 0xFFFFFFFF00000000ull;                          // parity 0: never-matching tag
  }
}

__global__ void __launch_bounds__(NTHR) gru_persist(
    const float* __restrict__ x, const float* __restrict__ h0,
    const float* __restrict__ Wih, const float* __restrict__ Whh,
    const float* __restrict__ bih, const float* __restrict__ bhh,
    const int* __restrict__ lens,
    float* __restrict__ out, float* __restrict__ outh,
    uint64_t* __restrict__ hbx) {
  __shared__ alignas(16) unsigned short x_lds[2][BROWS * LROW];
  __shared__ alignas(16) unsigned short h_lds[BROWS * LROW];
  __shared__ alignas(16) float s_lds[BROWS][4][JCH];   // [row][r,z,i_n,h_n][j]

  const int tid = threadIdx.x;
  const int lane = tid & 63;
  const int wv = tid >> 6;                 // wave 0..7
  const int gid = blockIdx.x & 3;          // batch group
  const int mem = blockIdx.x >> 2;         // member within group
  const int b0 = gid * BROWS;
  const int j0 = mem * JCH;

  // ---- per-thread gate-phase constants (thread <-> (row, j) fixed) ----
  const int grow = tid >> 5;               // local batch row 0..15
  const int gj = tid & 31;                 // local hidden 0..31
  const float br = bih[j0 + gj] + bhh[j0 + gj];
  const float bz = bih[512 + j0 + gj] + bhh[512 + j0 + gj];
  const float bi_n = bih[1024 + j0 + gj];
  const float bh_n = bhh[1024 + j0 + gj];
  float hprev = h0[(size_t)(b0 + grow) * HD + j0 + gj];   // f32 running state in-register
  const int lenr = lens[b0 + grow];        // int32 per harness integer convention
  float* const outp = out + (size_t)(b0 + grow) * Tsz * HD + j0 + gj;

  // ---- poll-phase constants: thread owns one 64B line (8 u64 = 16 h cols) ----
  const int prow = tid >> 5;               // local batch row 0..15
  const int pcu = (tid & 31) * 8;          // first u64 (col-pair) index in row
  const uint64_t* psrc = hbx + (size_t)(b0 + prow) * 256 + pcu;

  // ---- x prefetch constants (thread owns fixed (row stride-4, c4) pattern) ----
  const int xc4 = tid & 127;
  const int xr0 = tid >> 7;                // rows xr0, xr0+4, xr0+8, xr0+12
  const float* xbp[4];
#pragma unroll
  for (int i = 0; i < 4; ++i)
    xbp[i] = x + (size_t)(b0 + xr0 + 4 * i) * Tsz * HD + xc4 * 4;

  // ---- stationary weight fragments (held in VGPRs for the whole scan) ----
  const int c = lane & 15;                 // MFMA col (gate) / A-row (batch)
  const int kg = lane >> 4;                // k-group 0..3
  bf16x8 wfa[16], wfb[16];
  if (wv < 4) {                            // combined r/z: wv0,1 = r cols, wv2,3 = z cols
    const int wrow = (wv >> 1) * 512 + j0 + (wv & 1) * 16 + c;
#pragma unroll
    for (int ks = 0; ks < 16; ++ks) {
      const int k0 = ks * 32 + kg * 8;
      wfa[ks] = ldwf(Wih, wrow, k0);
      wfb[ks] = ldwf(Whh, wrow, k0);
    }
  } else if (wv < 6) {                     // i_n (x-part only)
    const int wrow = 1024 + j0 + (wv - 4) * 16 + c;
#pragma unroll
    for (int ks = 0; ks < 16; ++ks) wfa[ks] = ldwf(Wih, wrow, ks * 32 + kg * 8);
  } else {                                 // h_n (h-part only)
    const int wrow = 1024 + j0 + (wv - 6) * 16 + c;
#pragma unroll
    for (int ks = 0; ks < 16; ++ks) wfb[ks] = ldwf(Whh, wrow, ks * 32 + kg * 8);
  }

  stage_x0(x, b0, (uint32_t*)&x_lds[0][0], tid);   // prologue: x(0) -> parity 0

  // prologue prefetch: x(1) -> registers (consumed at t=0's A3)
  f32x4 xr[4];
#pragma unroll
  for (int i = 0; i < 4; ++i)
    xr[i] = *reinterpret_cast<const f32x4*>(xbp[i] + (size_t)1 * HD);

  float o_pend = 0.f;                      // deferred out[] value for step t-1

  __syncthreads();   // prologue staging visible to all waves before t=0 P0

  for (int t = 0; t < Tsz; ++t) {
    // ---- P0: x-part MFMAs (need no h(t-1)); overlap the exchange window ----
    f32x4 acc0 = {0.f, 0.f, 0.f, 0.f}, acc1 = {0.f, 0.f, 0.f, 0.f};
    {
      const unsigned short* xl = &x_lds[t & 1][0];
      if (wv < 6) {
#pragma unroll
        for (int ks = 0; ks < 16; ks += 2) {
          bf16x8 a0 = *reinterpret_cast<const bf16x8*>(xl + c * LROW + ks * 32 + kg * 8);
          bf16x8 a1 = *reinterpret_cast<const bf16x8*>(xl + c * LROW + (ks + 1) * 32 + kg * 8);
          acc0 = __builtin_amdgcn_mfma_f32_16x16x32_bf16(a0, wfa[ks], acc0, 0, 0, 0);
          acc1 = __builtin_amdgcn_mfma_f32_16x16x32_bf16(a1, wfa[ks + 1], acc1, 0, 0, 0);
        }
      }
    }

    // ---- A3 (poll-independent, so it hides under the spin wait below):
    //      convert prefetched x(t+1) -> LDS (opposite buffer from P0's) ----
    if (t + 1 < Tsz) {
      uint32_t* xl = (uint32_t*)&x_lds[(t + 1) & 1][0];
#pragma unroll
      for (int i = 0; i < 4; ++i) {
        u32x2 w;
        w.x = f2bf(xr[i].x) | (f2bf(xr[i].y) << 16);
        w.y = f2bf(xr[i].z) | (f2bf(xr[i].w) << 16);
        *reinterpret_cast<u32x2*>(xl + (xr0 + 4 * i) * LROWD + xc4 * 2) = w;
      }
    }

    // ---- A2: sentinel-first poll of tagged h(t-1). Outstanding vmem here is
    //      only the hbx packet store (~LLC ack, bounded by the flight itself):
    //      out store was deferred past this point, prefetch issued post-S1 ----
    {
      const uint64_t* src = psrc + (size_t)((t + 1) & 1) * HSLOT;
      const uint32_t want = (uint32_t)t;   // tag of h(t-1)
      uint64_t v[8];
      uint64_t s0;
      do {
        s0 = __hip_atomic_load(src, __ATOMIC_RELAXED, __HIP_MEMORY_SCOPE_AGENT);
      } while ((uint32_t)(s0 >> 32) != want);
      v[0] = s0;
      for (;;) {
        bool ok = true;
#pragma unroll
        for (int i = 1; i < 8; ++i)
          v[i] = __hip_atomic_load(src + i, __ATOMIC_RELAXED, __HIP_MEMORY_SCOPE_AGENT);
#pragma unroll
        for (int i = 1; i < 8; ++i) ok &= ((uint32_t)(v[i] >> 32) == want);
        if (ok) break;
      }
      uint32_t* dst = (uint32_t*)&h_lds[0] + prow * LROWD + pcu;
      u32x4 w0 = {(uint32_t)v[0], (uint32_t)v[1], (uint32_t)v[2], (uint32_t)v[3]};
      u32x4 w1 = {(uint32_t)v[4], (uint32_t)v[5], (uint32_t)v[6], (uint32_t)v[7]};
      *reinterpret_cast<u32x4*>(dst) = w0;
      *reinterpret_cast<u32x4*>(dst + 4) = w1;
    }

    // ---- deferred out store for step t-1: ack retires under P2+S2+C+P0,
    //      never in front of a poll (barriers below are lgkm-only) ----
    if (t > 0) outp[(size_t)(t - 1) * HD] = o_pend;

    BAR();   // S1: h_lds + x_lds(t+1) ready (lgkm only; no vmcnt drain)

    // ---- depth-2 prefetch x(t+2), issued AFTER S1 so no barrier drains it;
    //      retires during P2/S2/C/P0 before A3 of step t+1 consumes it ----
    if (t + 2 < Tsz) {
#pragma unroll
      for (int i = 0; i < 4; ++i)
        xr[i] = *reinterpret_cast<const f32x4*>(xbp[i] + (size_t)(t + 2) * HD);
    }

    // ---- P2: h-part MFMAs; all s_lds writes stay post-S1 (guards C(t-1) readers) ----
    {
      const unsigned short* hl = &h_lds[0];
      if (wv < 4 || wv >= 6) {
#pragma unroll
        for (int ks = 0; ks < 16; ks += 2) {
          bf16x8 a0 = *reinterpret_cast<const bf16x8*>(hl + c * LROW + ks * 32 + kg * 8);
          bf16x8 a1 = *reinterpret_cast<const bf16x8*>(hl + c * LROW + (ks + 1) * 32 + kg * 8);
          acc0 = __builtin_amdgcn_mfma_f32_16x16x32_bf16(a0, wfb[ks], acc0, 0, 0, 0);
          acc1 = __builtin_amdgcn_mfma_f32_16x16x32_bf16(a1, wfb[ks + 1], acc1, 0, 0, 0);
        }
      }
      const f32x4 acc = acc0 + acc1;
      const int slot = (wv < 4) ? (wv >> 1) : ((wv < 6) ? 2 : 3);
      const int col = (wv & 1) * 16 + c;
#pragma unroll
      for (int q = 0; q < 4; ++q) s_lds[kg * 4 + q][slot][col] = acc[q];
    }
    BAR();   // S2: s_lds ready (lgkm only)

    // ---- C: gates; hbx packet store issued first (exchange flight starts
    //      first in the in-order VMEM queue); out store deferred to next step ----
    {
      const float sr = s_lds[grow][0][gj] + br;
      const float sz = s_lds[grow][1][gj] + bz;
      const float si = s_lds[grow][2][gj] + bi_n;
      const float sh = s_lds[grow][3][gj] + bh_n;
      const float r = 1.f / (1.f + __expf(-sr));
      const float z = 1.f / (1.f + __expf(-sz));
      const float n = tanhf(si + r * sh);
      const float hnew = (1.f - z) * n + z * hprev;
      const bool m = (t < lenr);
      const float hk = m ? hnew : hprev;
      const uint32_t ub = f2bf(hk);
      const uint32_t ot = __shfl_xor(ub, 1);
      if ((t + 1 < Tsz) && ((lane & 1) == 0)) {
        const uint32_t word = ub | (ot << 16);
        const uint64_t pkt = ((uint64_t)(uint32_t)(t + 1) << 32) | (uint64_t)word;
        __hip_atomic_store(hbx + (size_t)(t & 1) * HSLOT + (size_t)(b0 + grow) * 256 +
                               ((j0 + gj) >> 1),
                           pkt, __ATOMIC_RELAXED, __HIP_MEMORY_SCOPE_AGENT);
      }
      o_pend = m ? hnew : 0.f;
      hprev = hk;
    }
    // no end-of-step barrier: the tagged dataflow exchange self-synchronizes members;
    // S1/S2's collectivity protects all intra-WG LDS buffer reuse across steps.
  }

  // epilogue: last step's deferred output + final state
  outp[(size_t)(Tsz - 1) * HD] = o_pend;
  outh[(size_t)(b0 + grow) * HD + j0 + gj] = hprev;
}

extern "C" void kernel_launch(void* const* d_in, const int* in_sizes, int n_in,
                              void* d_out, int out_size, void* d_ws, size_t ws_size,
                              hipStream_t stream) {
  const float* x = (const float*)d_in[0];
  const float* h0 = (const float*)d_in[1];
  const float* Wih = (const float*)d_in[2];
  const float* Whh = (const float*)d_in[3];
  const float* bih = (const float*)d_in[4];
  const float* bhh = (const float*)d_in[5];
  const int* lens = (const int*)d_in[6];
  float* out = (float*)d_out;
  float* outh = out + (size_t)Bsz * Tsz * HD;

  uint64_t* hbx = (uint64_t*)d_ws;                 // [2][Bsz][HD/2] tagged bf16 pairs, 256 KB

  gru_init<<<64, 256, 0, stream>>>(h0, hbx);
  gru_persist<<<NWG, NTHR, 0, stream>>>(x, h0, Wih, Whh, bih, bhh, lens,
                                        out, outh, hbx);
}

// Round 6
// 1289.481 us; speedup vs baseline: 1.7140x; 1.0958x over previous
//
#include <hip/hip_runtime.h>
#include <stdint.h>

#define Bsz 64
#define Tsz 512
#define HD  512
#define GROUPS 4
#define MEMBERS 16
#define BROWS 16          // batch rows per group
#define JCH 32            // hidden units per workgroup
#define NWG (GROUPS*MEMBERS)
#define NTHR 512
#define LROW 520          // LDS row stride in halfwords (512 + 8 pad)
#define LROWD 260         // same in dwords
#define HSLOT (Bsz*HD/2)  // 16384 u64 per parity buffer

typedef __attribute__((ext_vector_type(8))) short bf16x8;
typedef __attribute__((ext_vector_type(4))) float f32x4;
typedef __attribute__((ext_vector_type(4))) uint32_t u32x4;
typedef __attribute__((ext_vector_type(2))) uint32_t u32x2;

// lgkm-only barrier: all intra-WG LDS hazards need lgkmcnt(0)+s_barrier only.
// Global store acks / prefetch loads stay in flight across barriers.
#define BAR() asm volatile("s_waitcnt lgkmcnt(0)\n\ts_barrier" ::: "memory")

__device__ __forceinline__ uint32_t f2bf(float f) {
  uint32_t u = __builtin_bit_cast(uint32_t, f);
  return (u + 0x7FFFu + ((u >> 16) & 1u)) >> 16;   // RNE f32 -> bf16
}

// Load 8 consecutive f32 from W[row][k0..k0+7], convert to a bf16x8 MFMA B-fragment.
__device__ __forceinline__ bf16x8 ldwf(const float* __restrict__ W, int row, int k0) {
  const f32x4 a = *reinterpret_cast<const f32x4*>(W + (size_t)row * HD + k0);
  const f32x4 b = *reinterpret_cast<const f32x4*>(W + (size_t)row * HD + k0 + 4);
  bf16x8 r;
  r[0] = (short)f2bf(a.x); r[1] = (short)f2bf(a.y);
  r[2] = (short)f2bf(a.z); r[3] = (short)f2bf(a.w);
  r[4] = (short)f2bf(b.x); r[5] = (short)f2bf(b.y);
  r[6] = (short)f2bf(b.z); r[7] = (short)f2bf(b.w);
  return r;
}

// Prologue-only: stage x[b0..b0+15][0][:] (f32) into LDS as bf16.
__device__ __forceinline__ void stage_x0(const float* __restrict__ x, int b0,
                                         uint32_t* xl, int tid) {
#pragma unroll
  for (int i = 0; i < 4; ++i) {
    const int fl = tid + i * 512;        // float4 index over 16x128
    const int row = fl >> 7;
    const int c4 = fl & 127;
    const f32x4 v = *reinterpret_cast<const f32x4*>(
        x + (size_t)(b0 + row) * Tsz * HD + c4 * 4);
    u32x2 w;
    w.x = f2bf(v.x) | (f2bf(v.y) << 16);
    w.y = f2bf(v.z) | (f2bf(v.w) << 16);
    *reinterpret_cast<u32x2*>(xl + row * LROWD + c4 * 2) = w;
  }
}

// Workspace layout:
//   flg: u32[2][GROUPS][16]  — one 64B flag line per (parity, group)
//   hbx: u64[2][Bsz][256]    — tagged bf16 pairs: (tag << 32) | (2 packed bf16)
// h(s) lives at parity s&1 with tag s+1; h(-1)=h0 at parity 1 with tag 0.
__global__ void gru_init(const float* __restrict__ h0, uint32_t* __restrict__ flg,
                         uint64_t* __restrict__ hbx) {
  const int i = blockIdx.x * 256 + threadIdx.x;
  if (i < 2 * GROUPS * 16) flg[i] = (i < GROUPS * 16) ? 0xFFFFFFFFu : 0u;
  if (i < HSLOT) {
    const float a = h0[2 * i], b = h0[2 * i + 1];
    hbx[HSLOT + i] = (uint64_t)(f2bf(a) | (f2bf(b) << 16));  // parity 1: tag 0 | h0
    hbx[i] = 0xFFFFFFFF00000000ull;                          // parity 0: never-matching tag
  }
}

__global__ void __launch_bounds__(NTHR) gru_persist(
    const float* __restrict__ x, const float* __restrict__ h0,
    const float* __restrict__ Wih, const float* __restrict__ Whh,
    const float* __restrict__ bih, const float* __restrict__ bhh,
    const int* __restrict__ lens,
    float* __restrict__ out, float* __restrict__ outh,
    uint32_t* __restrict__ flg, uint64_t* __restrict__ hbx) {
  __shared__ alignas(16) unsigned short x_lds[2][BROWS * LROW];
  __shared__ alignas(16) unsigned short h_lds[BROWS * LROW];
  __shared__ alignas(16) float s_lds[BROWS][4][JCH];   // [row][r,z,i_n,h_n][j]

  const int tid = threadIdx.x;
  const int lane = tid & 63;
  const int wv = tid >> 6;                 // wave 0..7
  const int gid = blockIdx.x & 3;          // batch group
  const int mem = blockIdx.x >> 2;         // member within group
  const int b0 = gid * BROWS;
  const int j0 = mem * JCH;

  // ---- per-thread gate-phase constants (thread <-> (row, j) fixed) ----
  const int grow = tid >> 5;               // local batch row 0..15
  const int gj = tid & 31;                 // local hidden 0..31
  const float br = bih[j0 + gj] + bhh[j0 + gj];
  const float bz = bih[512 + j0 + gj] + bhh[512 + j0 + gj];
  const float bi_n = bih[1024 + j0 + gj];
  const float bh_n = bhh[1024 + j0 + gj];
  float hprev = h0[(size_t)(b0 + grow) * HD + j0 + gj];   // f32 running state in-register
  const int lenr = lens[b0 + grow];        // int32 per harness integer convention
  float* const outp = out + (size_t)(b0 + grow) * Tsz * HD + j0 + gj;

  // ---- coalesced h-read constants: 4 lanes share one 64B line (16B/lane) ----
  const int q = tid & 127;                 // 16B chunk index within a row (128 chunks)
  const int r0 = tid >> 7;                 // rows r0, r0+4, r0+8, r0+12

  // ---- x prefetch constants (thread owns fixed (row stride-4, c4) pattern) ----
  const int xc4 = tid & 127;
  const int xr0 = tid >> 7;
  const float* xbp[4];
#pragma unroll
  for (int i = 0; i < 4; ++i)
    xbp[i] = x + (size_t)(b0 + xr0 + 4 * i) * Tsz * HD + xc4 * 4;

  // ---- stationary weight fragments (held in VGPRs for the whole scan) ----
  const int c = lane & 15;                 // MFMA col (gate) / A-row (batch)
  const int kg = lane >> 4;                // k-group 0..3
  bf16x8 wfa[16], wfb[16];
  if (wv < 4) {                            // combined r/z: wv0,1 = r cols, wv2,3 = z cols
    const int wrow = (wv >> 1) * 512 + j0 + (wv & 1) * 16 + c;
#pragma unroll
    for (int ks = 0; ks < 16; ++ks) {
      const int k0 = ks * 32 + kg * 8;
      wfa[ks] = ldwf(Wih, wrow, k0);
      wfb[ks] = ldwf(Whh, wrow, k0);
    }
  } else if (wv < 6) {                     // i_n (x-part only)
    const int wrow = 1024 + j0 + (wv - 4) * 16 + c;
#pragma unroll
    for (int ks = 0; ks < 16; ++ks) wfa[ks] = ldwf(Wih, wrow, ks * 32 + kg * 8);
  } else {                                 // h_n (h-part only)
    const int wrow = 1024 + j0 + (wv - 6) * 16 + c;
#pragma unroll
    for (int ks = 0; ks < 16; ++ks) wfb[ks] = ldwf(Whh, wrow, ks * 32 + kg * 8);
  }

  stage_x0(x, b0, (uint32_t*)&x_lds[0][0], tid);   // prologue: x(0) -> parity 0

  // prologue prefetch: x(1) -> registers (consumed at t=0's A3)
  f32x4 xr[4];
#pragma unroll
  for (int i = 0; i < 4; ++i)
    xr[i] = *reinterpret_cast<const f32x4*>(xbp[i] + (size_t)1 * HD);

  float o_pend = 0.f;                      // deferred out[] value for step t-1

  __syncthreads();   // prologue staging visible to all waves before t=0 P0

  for (int t = 0; t < Tsz; ++t) {
    // ---- P0: x-part MFMAs (need no h(t-1)); overlap the exchange window ----
    f32x4 acc0 = {0.f, 0.f, 0.f, 0.f}, acc1 = {0.f, 0.f, 0.f, 0.f};
    {
      const unsigned short* xl = &x_lds[t & 1][0];
      if (wv < 6) {
#pragma unroll
        for (int ks = 0; ks < 16; ks += 2) {
          bf16x8 a0 = *reinterpret_cast<const bf16x8*>(xl + c * LROW + ks * 32 + kg * 8);
          bf16x8 a1 = *reinterpret_cast<const bf16x8*>(xl + c * LROW + (ks + 1) * 32 + kg * 8);
          acc0 = __builtin_amdgcn_mfma_f32_16x16x32_bf16(a0, wfa[ks], acc0, 0, 0, 0);
          acc1 = __builtin_amdgcn_mfma_f32_16x16x32_bf16(a1, wfa[ks + 1], acc1, 0, 0, 0);
        }
      }
    }

    // ---- A3: convert prefetched x(t+1) -> LDS (opposite buffer from P0's) ----
    if (t + 1 < Tsz) {
      uint32_t* xl = (uint32_t*)&x_lds[(t + 1) & 1][0];
#pragma unroll
      for (int i = 0; i < 4; ++i) {
        u32x2 w;
        w.x = f2bf(xr[i].x) | (f2bf(xr[i].y) << 16);
        w.y = f2bf(xr[i].z) | (f2bf(xr[i].w) << 16);
        *reinterpret_cast<u32x2*>(xl + (xr0 + 4 * i) * LROWD + xc4 * 2) = w;
      }
    }

    const uint32_t want = (uint32_t)t;     // tag of h(t-1)

    // ---- A2a: aggregate-flag gate. One 64B line per group; wave-uniform
    //      address -> 4 fabric transactions per wave per iteration (vs 64
    //      distinct sentinel lines before). Flag is a HINT; data tags below
    //      carry correctness ----
    {
      const uint32_t* fl = flg + ((((t + 1) & 1) * GROUPS + gid) << 4);
      for (;;) {
        u32x4 f0, f1, f2, f3;
        asm volatile(
            "global_load_dwordx4 %0, %4, off sc0 sc1\n\t"
            "global_load_dwordx4 %1, %4, off offset:16 sc0 sc1\n\t"
            "global_load_dwordx4 %2, %4, off offset:32 sc0 sc1\n\t"
            "global_load_dwordx4 %3, %4, off offset:48 sc0 sc1\n\t"
            "s_waitcnt vmcnt(0)"
            : "=&v"(f0), "=&v"(f1), "=&v"(f2), "=&v"(f3)
            : "v"(fl)
            : "memory");
        bool ok = true;
#pragma unroll
        for (int i = 0; i < 4; ++i)
          ok &= (f0[i] == want) & (f1[i] == want) & (f2[i] == want) & (f3[i] == want);
        if (ok) break;
      }
    }

    // ---- A2b: coalesced tagged read of h(t-1). 4 consecutive lanes cover one
    //      64B line (16B each) -> TA merges to one fabric read per line.
    //      Tag verify + retry preserves correctness if flag raced ahead ----
    {
      const uint64_t* bp = hbx + (size_t)((t + 1) & 1) * HSLOT;
      const uint64_t* a0 = bp + (size_t)(b0 + r0) * 256 + q * 2;
      const uint64_t* a1 = a0 + 4 * 256;
      const uint64_t* a2 = a0 + 8 * 256;
      const uint64_t* a3 = a0 + 12 * 256;
      u32x4 d0, d1, d2, d3;
      for (;;) {
        asm volatile(
            "global_load_dwordx4 %0, %4, off sc0 sc1\n\t"
            "global_load_dwordx4 %1, %5, off sc0 sc1\n\t"
            "global_load_dwordx4 %2, %6, off sc0 sc1\n\t"
            "global_load_dwordx4 %3, %7, off sc0 sc1\n\t"
            "s_waitcnt vmcnt(0)"
            : "=&v"(d0), "=&v"(d1), "=&v"(d2), "=&v"(d3)
            : "v"(a0), "v"(a1), "v"(a2), "v"(a3)
            : "memory");
        const bool ok = (d0[1] == want) & (d0[3] == want) & (d1[1] == want) &
                        (d1[3] == want) & (d2[1] == want) & (d2[3] == want) &
                        (d3[1] == want) & (d3[3] == want);
        if (ok) break;
      }
      uint32_t* hd = (uint32_t*)&h_lds[0] + q * 2;
      u32x2 w;
      w.x = d0[0]; w.y = d0[2];
      *reinterpret_cast<u32x2*>(hd + (r0) * LROWD) = w;
      w.x = d1[0]; w.y = d1[2];
      *reinterpret_cast<u32x2*>(hd + (r0 + 4) * LROWD) = w;
      w.x = d2[0]; w.y = d2[2];
      *reinterpret_cast<u32x2*>(hd + (r0 + 8) * LROWD) = w;
      w.x = d3[0]; w.y = d3[2];
      *reinterpret_cast<u32x2*>(hd + (r0 + 12) * LROWD) = w;
    }

    // ---- deferred out store for step t-1: ack retires under P2+S2+C+P0 ----
    if (t > 0) outp[(size_t)(t - 1) * HD] = o_pend;

    BAR();   // S1: h_lds + x_lds(t+1) ready (lgkm only; no vmcnt drain)

    // ---- depth-2 prefetch x(t+2), issued AFTER S1 so no barrier drains it ----
    if (t + 2 < Tsz) {
#pragma unroll
      for (int i = 0; i < 4; ++i)
        xr[i] = *reinterpret_cast<const f32x4*>(xbp[i] + (size_t)(t + 2) * HD);
    }

    // ---- P2: h-part MFMAs; all s_lds writes stay post-S1 ----
    {
      const unsigned short* hl = &h_lds[0];
      if (wv < 4 || wv >= 6) {
#pragma unroll
        for (int ks = 0; ks < 16; ks += 2) {
          bf16x8 a0 = *reinterpret_cast<const bf16x8*>(hl + c * LROW + ks * 32 + kg * 8);
          bf16x8 a1 = *reinterpret_cast<const bf16x8*>(hl + c * LROW + (ks + 1) * 32 + kg * 8);
          acc0 = __builtin_amdgcn_mfma_f32_16x16x32_bf16(a0, wfb[ks], acc0, 0, 0, 0);
          acc1 = __builtin_amdgcn_mfma_f32_16x16x32_bf16(a1, wfb[ks + 1], acc1, 0, 0, 0);
        }
      }
      const f32x4 acc = acc0 + acc1;
      const int slot = (wv < 4) ? (wv >> 1) : ((wv < 6) ? 2 : 3);
      const int col = (wv & 1) * 16 + c;
#pragma unroll
      for (int qq = 0; qq < 4; ++qq) s_lds[kg * 4 + qq][slot][col] = acc[qq];
    }
    BAR();   // S2: s_lds ready (lgkm only)

    // ---- C: gates; tagged packet store first, then member flag (hint) ----
    {
      const float sr = s_lds[grow][0][gj] + br;
      const float sz = s_lds[grow][1][gj] + bz;
      const float si = s_lds[grow][2][gj] + bi_n;
      const float sh = s_lds[grow][3][gj] + bh_n;
      const float r = 1.f / (1.f + __expf(-sr));
      const float z = 1.f / (1.f + __expf(-sz));
      const float n = tanhf(si + r * sh);
      const float hnew = (1.f - z) * n + z * hprev;
      const bool m = (t < lenr);
      const float hk = m ? hnew : hprev;
      const uint32_t ub = f2bf(hk);
      const uint32_t ot = __shfl_xor(ub, 1);
      if ((t + 1 < Tsz) && ((lane & 1) == 0)) {
        const uint32_t word = ub | (ot << 16);
        const uint64_t pkt = ((uint64_t)(uint32_t)(t + 1) << 32) | (uint64_t)word;
        __hip_atomic_store(hbx + (size_t)(t & 1) * HSLOT + (size_t)(b0 + grow) * 256 +
                               ((j0 + gj) >> 1),
                           pkt, __ATOMIC_RELAXED, __HIP_MEMORY_SCOPE_AGENT);
      }
      if ((t + 1 < Tsz) && (tid == 0)) {   // tid0's packet precedes in program order;
                                           // stragglers covered by tag verify
        __hip_atomic_store(flg + (((t & 1) * GROUPS + gid) << 4) + mem,
                           (uint32_t)(t + 1), __ATOMIC_RELAXED,
                           __HIP_MEMORY_SCOPE_AGENT);
      }
      o_pend = m ? hnew : 0.f;
      hprev = hk;
    }
    // no end-of-step barrier: the tagged dataflow exchange self-synchronizes members;
    // S1/S2's collectivity protects all intra-WG LDS buffer reuse across steps.
  }

  // epilogue: last step's deferred output + final state
  outp[(size_t)(Tsz - 1) * HD] = o_pend;
  outh[(size_t)(b0 + grow) * HD + j0 + gj] = hprev;
}

extern "C" void kernel_launch(void* const* d_in, const int* in_sizes, int n_in,
                              void* d_out, int out_size, void* d_ws, size_t ws_size,
                              hipStream_t stream) {
  const float* x = (const float*)d_in[0];
  const float* h0 = (const float*)d_in[1];
  const float* Wih = (const float*)d_in[2];
  const float* Whh = (const float*)d_in[3];
  const float* bih = (const float*)d_in[4];
  const float* bhh = (const float*)d_in[5];
  const int* lens = (const int*)d_in[6];
  float* out = (float*)d_out;
  float* outh = out + (size_t)Bsz * Tsz * HD;

  uint32_t* flg = (uint32_t*)d_ws;                         // [2][GROUPS][16], 512 B
  uint64_t* hbx = (uint64_t*)((char*)d_ws + 512);          // [2][Bsz][256] tagged pairs

  gru_init<<<64, 256, 0, stream>>>(h0, flg, hbx);
  gru_persist<<<NWG, NTHR, 0, stream>>>(x, h0, Wih, Whh, bih, bhh, lens,
                                        out, outh, flg, hbx);
}